// Round 11
// baseline (202.850 us; speedup 1.0000x reference)
//
#include <hip/hip_runtime.h>
#include <math.h>

using f16   = _Float16;
using f16x2 = __attribute__((ext_vector_type(2))) _Float16;
using f16x4 = __attribute__((ext_vector_type(4))) _Float16;
using f16x8 = __attribute__((ext_vector_type(8))) _Float16;
using f32x4 = __attribute__((ext_vector_type(4))) float;

#define NW    343           // tokens per window (7*7*7)
#define NWP   352           // padded to 22*16
#define VTP   356           // V^T LDS pitch
#define HEADS 8
#define MTOT  43904         // 128 windows * 343
#define LOG2E 1.4426950408889634f
#define QSC   (0.17677669529663687f * 1.4426950408889634f)  // dh^-0.5 * log2(e)

typedef const __attribute__((address_space(1))) unsigned int* gp1_t;
typedef __attribute__((address_space(3))) unsigned int* lp3_t;
__device__ __forceinline__ void gload_lds16(const void* g, void* l) {
    __builtin_amdgcn_global_load_lds((gp1_t)g, (lp3_t)l, 16, 0, 0);
}

// cvt_pkrtz returns __fp16x2; bit-cast to our _Float16-based f16x2 (same layout).
__device__ __forceinline__ f16x2 pk_cvt(float a, float b) {
    return __builtin_bit_cast(f16x2, __builtin_amdgcn_cvt_pkrtz(a, b));
}

__device__ __forceinline__ float dot2acc(f16x2 a, float acc) {
#if __has_builtin(__builtin_amdgcn_fdot2)
    const f16x2 one2 = { (f16)1.f, (f16)1.f };
    return __builtin_amdgcn_fdot2(a, one2, acc, false);
#else
    return acc + (float)a[0] + (float)a[1];
#endif
}

// ---------------- fused prep: wqkv^T, wout^T, exp-bias table ----------------
// One launch instead of three (cvt_wT x2 + bias_k); block-uniform range branch.
__global__ void prep_k(const float* __restrict__ wqkv, const float* __restrict__ wout,
                       const float* __restrict__ tab,
                       f16* __restrict__ wqkvT, f16* __restrict__ woutT,
                       f16* __restrict__ ebP) {
    int b = blockIdx.x;
    if (b < 768) {                       // wqkv (256x768) -> wqkvT (768x256), Q-scale
        int id = b * 256 + threadIdx.x;
        int n = id >> 8, k = id & 255;
        float v = wqkv[k * 768 + n];
        if (n < 256) v *= QSC;
        wqkvT[n * 256 + k] = (f16)v;
    } else if (b < 1024) {               // wout (256x256) -> woutT
        int id = (b - 768) * 256 + threadIdx.x;
        int n = id >> 8, k = id & 255;
        woutT[n * 256 + k] = (f16)wout[k * 256 + n];
    } else {                             // exp-domain bias: eb[h][i][j] = e^bias
        int id = (b - 1024) * 256 + threadIdx.x;
        int h = id / (NWP * NWP);
        int rem = id - h * NWP * NWP;
        int i = rem / NWP, j = rem - (rem / NWP) * NWP;
        float v;
        if (j >= NW) v = 0.f;            // exact key mask
        else if (i >= NW) v = 1.f;       // rows discarded
        else {
            int a1 = i / 49, a2 = (i / 7) % 7, a3 = i % 7;
            int b1 = j / 49, b2 = (j / 7) % 7, b3 = j % 7;
            int idx = (a1 - b1 + 6) * 169 + (a2 - b2 + 6) * 13 + (a3 - b3 + 6);
            v = exp2f(tab[idx * 8 + h] * LOG2E);
        }
        ebP[id] = (f16)v;
    }
}

// ---- GEMM: C(M x N) = A(M x 256) * Bt(N x 256)^T, 128x128 tile ----
// AF32: A is read as f32 and converted during staging (kills the cvt_x kernel;
// reg-staged A also lets the compiler pipeline A-loads across ks, which
// global_load_lds forbids). B always f16 via lds-DMA.
// 1-D grid + bijective XCD chunk swizzle (m204), N-tile-fast ordering.
template<bool OUT_F32, bool AF32>
__launch_bounds__(256)
__global__ void gemm_k(const void* __restrict__ Ap, const f16* __restrict__ Bt,
                       void* __restrict__ Cp, int N, int NT) {
    __shared__ f16 As[128 * 32];
    __shared__ f16 Bs[128 * 32];
    const int nwg = gridDim.x;
    const int bid = blockIdx.x;
    const int q8 = nwg >> 3, r8 = nwg & 7;
    const int xcd = bid & 7, pos = bid >> 3;
    const int wg = (xcd < r8 ? xcd * (q8 + 1) : r8 * (q8 + 1) + (xcd - r8) * q8) + pos;
    const int mt = wg / NT, nt = wg - mt * NT;
    const int m0 = mt * 128;
    const int n0 = nt * 128;
    const int t = threadIdx.x;
    const int wave = t >> 6, lane = t & 63;
    const int q = lane >> 4, c = lane & 15;
    const int wm = (wave >> 1) * 64, wn = (wave & 1) * 64;
    const int r0 = t >> 2;
    const int c8 = (t & 3) * 8;

    f32x4 acc[4][4] = {};
#pragma unroll
    for (int ks = 0; ks < 256; ks += 32) {
        if constexpr (AF32) {
            const float* Af = (const float*)Ap;
            float4 u0 = *(const float4*)&Af[(size_t)(m0 + r0) * 256 + ks + c8];
            float4 u1 = *(const float4*)&Af[(size_t)(m0 + r0) * 256 + ks + c8 + 4];
            float4 u2 = *(const float4*)&Af[(size_t)(m0 + r0 + 64) * 256 + ks + c8];
            float4 u3 = *(const float4*)&Af[(size_t)(m0 + r0 + 64) * 256 + ks + c8 + 4];
            f16x8 h0 = { (f16)u0.x, (f16)u0.y, (f16)u0.z, (f16)u0.w,
                         (f16)u1.x, (f16)u1.y, (f16)u1.z, (f16)u1.w };
            f16x8 h1 = { (f16)u2.x, (f16)u2.y, (f16)u2.z, (f16)u2.w,
                         (f16)u3.x, (f16)u3.y, (f16)u3.z, (f16)u3.w };
            *(f16x8*)&As[r0 * 32 + c8] = h0;
            *(f16x8*)&As[(r0 + 64) * 32 + c8] = h1;
        } else {
            const f16* Af = (const f16*)Ap;
            gload_lds16(&Af[(size_t)(m0 + r0) * 256 + ks + c8],      &As[r0 * 32 + c8]);
            gload_lds16(&Af[(size_t)(m0 + r0 + 64) * 256 + ks + c8], &As[(r0 + 64) * 32 + c8]);
        }
        gload_lds16(&Bt[(size_t)(n0 + r0) * 256 + ks + c8],       &Bs[r0 * 32 + c8]);
        gload_lds16(&Bt[(size_t)(n0 + r0 + 64) * 256 + ks + c8],  &Bs[(r0 + 64) * 32 + c8]);
        __syncthreads();
        f16x8 af[4], bf[4];
#pragma unroll
        for (int a = 0; a < 4; a++) af[a] = *(const f16x8*)&As[(wm + a * 16 + c) * 32 + q * 8];
#pragma unroll
        for (int b = 0; b < 4; b++) bf[b] = *(const f16x8*)&Bs[(wn + b * 16 + c) * 32 + q * 8];
#pragma unroll
        for (int a = 0; a < 4; a++)
#pragma unroll
            for (int b = 0; b < 4; b++)
                acc[a][b] = __builtin_amdgcn_mfma_f32_16x16x32_f16(af[a], bf[b], acc[a][b], 0, 0, 0);
        __syncthreads();
    }
#pragma unroll
    for (int a = 0; a < 4; a++)
#pragma unroll
        for (int b = 0; b < 4; b++) {
            int row0 = m0 + wm + a * 16 + q * 4;
            int col = n0 + wn + b * 16 + c;
#pragma unroll
            for (int r = 0; r < 4; r++) {
                float v = acc[a][b][r];
                if (OUT_F32) ((float*)Cp)[(size_t)(row0 + r) * N + col] = v;
                else         ((f16*)Cp)[(size_t)(row0 + r) * N + col] = (f16)v;
            }
        }
}

// -------- fused attention: 1 block = (window, head), 4 waves share K/V LDS --------
// v9 (verified 57.3us): v5 structure + packed-f16 softmax (exp-domain bias).
// Parked: latency-bound in the [3-resident,+1] round structure; ILP/residency/
// VALU attacks all exhausted (R2/R5/R7/R8/R10).
template<bool HASB>
__device__ __forceinline__ void attn_tiles(
    const f16* __restrict__ qkv, const f16* __restrict__ ebH,
    f16* __restrict__ ctx, const f16* Ks, const f16* Vt,
    size_t base, int w, int h, int q, int c, int ta, int tb)
{
    const int iqa = ta * 16 + c;
    const int iqb = tb * 16 + c;
    const int iqac = iqa < NW ? iqa : NW - 1;
    const int iqbc = iqb < NW ? iqb : NW - 1;
    f16x8 qfa = *(const f16x8*)&qkv[base + (size_t)iqac * 768 + h * 32 + q * 8];
    f16x8 qfb{};
    if constexpr (HASB) qfb = *(const f16x8*)&qkv[base + (size_t)iqbc * 768 + h * 32 + q * 8];
    const f16* browA = ebH + (size_t)iqa * NWP;
    const f16* browB = ebH + (size_t)iqb * NWP;

    f32x4 o0a = {0.f,0.f,0.f,0.f}, o1a = {0.f,0.f,0.f,0.f};
    f32x4 o0b = {0.f,0.f,0.f,0.f}, o1b = {0.f,0.f,0.f,0.f};
    float lsa = 0.f, lsb = 0.f;
    const f32x4 z = {0.f, 0.f, 0.f, 0.f};
#pragma unroll
    for (int jt = 0; jt < NWP / 16; jt++) {
        const int jb = jt * 16;
        f16x8 kf = *(const f16x8*)&Ks[(jb + c) * 32 + q * 8];
        f16x4 v0 = *(const f16x4*)&Vt[c * VTP + jb + q * 4];
        f16x4 v1 = *(const f16x4*)&Vt[(16 + c) * VTP + jb + q * 4];

        f16x4 eba = *(const f16x4*)&browA[jb + q * 4];
        f32x4 sa = __builtin_amdgcn_mfma_f32_16x16x32_f16(kf, qfa, z, 0, 0, 0);
        f16x2 pla = pk_cvt(__builtin_amdgcn_exp2f(sa[0]), __builtin_amdgcn_exp2f(sa[1]));
        f16x2 pha = pk_cvt(__builtin_amdgcn_exp2f(sa[2]), __builtin_amdgcn_exp2f(sa[3]));
        f16x2 ela = { eba[0], eba[1] }, eha = { eba[2], eba[3] };
        pla *= ela; pha *= eha;                 // v_pk_mul_f16
        lsa = dot2acc(pla, lsa);
        lsa = dot2acc(pha, lsa);
        f16x4 pfa = { pla[0], pla[1], pha[0], pha[1] };
        o0a = __builtin_amdgcn_mfma_f32_16x16x16f16(v0, pfa, o0a, 0, 0, 0);
        o1a = __builtin_amdgcn_mfma_f32_16x16x16f16(v1, pfa, o1a, 0, 0, 0);

        if constexpr (HASB) {
            f16x4 ebb = *(const f16x4*)&browB[jb + q * 4];
            f32x4 sb = __builtin_amdgcn_mfma_f32_16x16x32_f16(kf, qfb, z, 0, 0, 0);
            f16x2 plb = pk_cvt(__builtin_amdgcn_exp2f(sb[0]), __builtin_amdgcn_exp2f(sb[1]));
            f16x2 phb = pk_cvt(__builtin_amdgcn_exp2f(sb[2]), __builtin_amdgcn_exp2f(sb[3]));
            f16x2 elb = { ebb[0], ebb[1] }, ehb = { ebb[2], ebb[3] };
            plb *= elb; phb *= ehb;
            lsb = dot2acc(plb, lsb);
            lsb = dot2acc(phb, lsb);
            f16x4 pfb = { plb[0], plb[1], phb[0], phb[1] };
            o0b = __builtin_amdgcn_mfma_f32_16x16x16f16(v0, pfb, o0b, 0, 0, 0);
            o1b = __builtin_amdgcn_mfma_f32_16x16x16f16(v1, pfb, o1b, 0, 0, 0);
        }
    }
    lsa += __shfl_xor(lsa, 16);
    lsa += __shfl_xor(lsa, 32);
    if (iqa < NW) {
        float inv = 1.f / lsa;
        size_t ob = (size_t)(w * NW + iqa) * 256 + h * 32;
        f16x4 s0 = { (f16)(o0a[0] * inv), (f16)(o0a[1] * inv),
                     (f16)(o0a[2] * inv), (f16)(o0a[3] * inv) };
        f16x4 s1 = { (f16)(o1a[0] * inv), (f16)(o1a[1] * inv),
                     (f16)(o1a[2] * inv), (f16)(o1a[3] * inv) };
        *(f16x4*)&ctx[ob + q * 4] = s0;
        *(f16x4*)&ctx[ob + 16 + q * 4] = s1;
    }
    if constexpr (HASB) {
        lsb += __shfl_xor(lsb, 16);
        lsb += __shfl_xor(lsb, 32);
        if (iqb < NW) {
            float inv = 1.f / lsb;
            size_t ob = (size_t)(w * NW + iqb) * 256 + h * 32;
            f16x4 s0 = { (f16)(o0b[0] * inv), (f16)(o0b[1] * inv),
                         (f16)(o0b[2] * inv), (f16)(o0b[3] * inv) };
            f16x4 s1 = { (f16)(o1b[0] * inv), (f16)(o1b[1] * inv),
                         (f16)(o1b[2] * inv), (f16)(o1b[3] * inv) };
            *(f16x4*)&ctx[ob + q * 4] = s0;
            *(f16x4*)&ctx[ob + 16 + q * 4] = s1;
        }
    }
}

__launch_bounds__(256, 3)
__global__ void attn_k(const f16* __restrict__ qkv, const f16* __restrict__ ebP,
                       f16* __restrict__ ctx) {
    const int w = blockIdx.x >> 3;
    const int h = blockIdx.x & 7;
    __shared__ f16 Ks[NWP * 32];       // [key][feat]
    __shared__ f16 Vt[32 * VTP];       // [dh][key] (transposed)
    const int t = threadIdx.x;
    const size_t base = (size_t)(w * NW) * 768;

    for (int u = t; u < NWP * 4; u += 256) {
        int row = u >> 2, un = u & 3;
        int rc = row < NW ? row : NW - 1;
        gload_lds16(&qkv[base + (size_t)rc * 768 + 256 + h * 32 + un * 8], &Ks[u * 8]);
    }
    for (int u = t; u < NWP * 4; u += 256) {
        int row = u >> 2, un = u & 3;
        if (row < NW) {
            uint4 val = *(const uint4*)&qkv[base + (size_t)row * 768 + 512 + h * 32 + un * 8];
            const f16* pv = (const f16*)&val;
#pragma unroll
            for (int e = 0; e < 8; e++) Vt[(un * 8 + e) * VTP + row] = pv[e];
        } else {
#pragma unroll
            for (int e = 0; e < 8; e++) Vt[(un * 8 + e) * VTP + row] = (f16)0.f;
        }
    }
    __syncthreads();

    const int wave = t >> 6, lane = t & 63;
    const int q = lane >> 4, c = lane & 15;
    const f16* ebH = ebP + (size_t)h * NWP * NWP;

#pragma unroll
    for (int pass = 0; pass < 3; pass++) {
        int p = wave + 4 * pass;
        if (p < 10)
            attn_tiles<true >(qkv, ebH, ctx, Ks, Vt, base, w, h, q, c, 2 * p, 2 * p + 1);
        else
            attn_tiles<false>(qkv, ebH, ctx, Ks, Vt, base, w, h, q, c, p + 10, p + 10);
    }
}

// ---------------- launch: 4 kernels (was 7) ----------------
extern "C" void kernel_launch(void* const* d_in, const int* in_sizes, int n_in,
                              void* d_out, int out_size, void* d_ws, size_t ws_size,
                              hipStream_t stream) {
    const float* x    = (const float*)d_in[0];
    const float* wqkv = (const float*)d_in[1];
    const float* wout = (const float*)d_in[2];
    const float* tab  = (const float*)d_in[3];

    char* ws = (char*)d_ws;
    size_t off = 0;
    f16*   wqkvT  = (f16*)(ws + off);   off += (size_t)768 * 256 * 2;
    f16*   woutT  = (f16*)(ws + off);   off += (size_t)256 * 256 * 2;
    f16*   ebP    = (f16*)(ws + off);   off += (size_t)8 * NWP * NWP * 2;
    f16*   qkvb   = (f16*)(ws + off);   off += (size_t)MTOT * 768 * 2;
    f16*   ctxb   = (f16*)(ws + off);   off += (size_t)MTOT * 256 * 2;
    if (ws_size < off) return;

    prep_k<<<1024 + 8 * NWP * NWP / 256, 256, 0, stream>>>(wqkv, wout, tab,
                                                           wqkvT, woutT, ebP);
    gemm_k<false, true ><<<MTOT / 128 * 6, 256, 0, stream>>>(x, wqkvT, qkvb, 768, 6);
    attn_k<<<128 * HEADS, 256, 0, stream>>>(qkvb, ebP, ctxb);
    gemm_k<true,  false><<<MTOT / 128 * 2, 256, 0, stream>>>(ctxb, woutT, d_out, 256, 2);
}

// Round 13
// 191.192 us; speedup vs baseline: 1.0610x; 1.0610x over previous
//
#include <hip/hip_runtime.h>
#include <math.h>

using f16   = _Float16;
using f16x2 = __attribute__((ext_vector_type(2))) _Float16;
using f16x4 = __attribute__((ext_vector_type(4))) _Float16;
using f16x8 = __attribute__((ext_vector_type(8))) _Float16;
using f32x4 = __attribute__((ext_vector_type(4))) float;

#define NW    343           // tokens per window (7*7*7)
#define NWP   352           // padded to 22*16
#define VTP   356           // V^T LDS pitch
#define HEADS 8
#define MTOT  43904         // 128 windows * 343
#define LOG2E 1.4426950408889634f
#define QSC   (0.17677669529663687f * 1.4426950408889634f)  // dh^-0.5 * log2(e)

typedef const __attribute__((address_space(1))) unsigned int* gp1_t;
typedef __attribute__((address_space(3))) unsigned int* lp3_t;
__device__ __forceinline__ void gload_lds16(const void* g, void* l) {
    __builtin_amdgcn_global_load_lds((gp1_t)g, (lp3_t)l, 16, 0, 0);
}

// cvt_pkrtz returns __fp16x2; bit-cast to our _Float16-based f16x2 (same layout).
__device__ __forceinline__ f16x2 pk_cvt(float a, float b) {
    return __builtin_bit_cast(f16x2, __builtin_amdgcn_cvt_pkrtz(a, b));
}

__device__ __forceinline__ float dot2acc(f16x2 a, float acc) {
#if __has_builtin(__builtin_amdgcn_fdot2)
    const f16x2 one2 = { (f16)1.f, (f16)1.f };
    return __builtin_amdgcn_fdot2(a, one2, acc, false);
#else
    return acc + (float)a[0] + (float)a[1];
#endif
}

// ---------------- x -> f16 (restored: R11 showed f32-A gemm1 adds ~25us of
// stall cycles to the FOLLOWING attn dispatch — same busy cycles, +45% stalls;
// the f16 pipeline keeps attn at its verified 57us) ----------------
__global__ void cvt_x(const float* __restrict__ x, f16* __restrict__ xb) {
    int id = blockIdx.x * 256 + threadIdx.x;
    float4 v = *(const float4*)(x + id * 4);
    f16x4 o = { (f16)v.x, (f16)v.y, (f16)v.z, (f16)v.w };
    *(f16x4*)(xb + id * 4) = o;
}

// ---------------- fused prep: wqkv^T, wout^T, exp-bias table ----------------
// One launch instead of three; block-uniform range branch.
__global__ void prep_k(const float* __restrict__ wqkv, const float* __restrict__ wout,
                       const float* __restrict__ tab,
                       f16* __restrict__ wqkvT, f16* __restrict__ woutT,
                       f16* __restrict__ ebP) {
    int b = blockIdx.x;
    if (b < 768) {                       // wqkv (256x768) -> wqkvT (768x256), Q-scale
        int id = b * 256 + threadIdx.x;
        int n = id >> 8, k = id & 255;
        float v = wqkv[k * 768 + n];
        if (n < 256) v *= QSC;
        wqkvT[n * 256 + k] = (f16)v;
    } else if (b < 1024) {               // wout (256x256) -> woutT
        int id = (b - 768) * 256 + threadIdx.x;
        int n = id >> 8, k = id & 255;
        woutT[n * 256 + k] = (f16)wout[k * 256 + n];
    } else {                             // exp-domain bias: eb[h][i][j] = e^bias
        int id = (b - 1024) * 256 + threadIdx.x;
        int h = id / (NWP * NWP);
        int rem = id - h * NWP * NWP;
        int i = rem / NWP, j = rem - (rem / NWP) * NWP;
        float v;
        if (j >= NW) v = 0.f;            // exact key mask
        else if (i >= NW) v = 1.f;       // rows discarded
        else {
            int a1 = i / 49, a2 = (i / 7) % 7, a3 = i % 7;
            int b1 = j / 49, b2 = (j / 7) % 7, b3 = j % 7;
            int idx = (a1 - b1 + 6) * 169 + (a2 - b2 + 6) * 13 + (a3 - b3 + 6);
            v = exp2f(tab[idx * 8 + h] * LOG2E);
        }
        ebP[id] = (f16)v;
    }
}

// ---- GEMM: C(M x N) = A(M x 256) * Bt(N x 256)^T, 128x128 tile, lds-DMA ----
// 1-D grid + bijective XCD chunk swizzle (m204), N-tile-fast ordering.
template<bool OUT_F32>
__launch_bounds__(256)
__global__ void gemm_k(const f16* __restrict__ A, const f16* __restrict__ Bt,
                       void* __restrict__ Cp, int N, int NT) {
    __shared__ f16 As[128 * 32];
    __shared__ f16 Bs[128 * 32];
    const int nwg = gridDim.x;
    const int bid = blockIdx.x;
    const int q8 = nwg >> 3, r8 = nwg & 7;
    const int xcd = bid & 7, pos = bid >> 3;
    const int wg = (xcd < r8 ? xcd * (q8 + 1) : r8 * (q8 + 1) + (xcd - r8) * q8) + pos;
    const int mt = wg / NT, nt = wg - mt * NT;
    const int m0 = mt * 128;
    const int n0 = nt * 128;
    const int t = threadIdx.x;
    const int wave = t >> 6, lane = t & 63;
    const int q = lane >> 4, c = lane & 15;
    const int wm = (wave >> 1) * 64, wn = (wave & 1) * 64;
    const int r0 = t >> 2;
    const int c8 = (t & 3) * 8;

    f32x4 acc[4][4] = {};
#pragma unroll
    for (int ks = 0; ks < 256; ks += 32) {
        gload_lds16(&A[(size_t)(m0 + r0) * 256 + ks + c8],        &As[r0 * 32 + c8]);
        gload_lds16(&A[(size_t)(m0 + r0 + 64) * 256 + ks + c8],   &As[(r0 + 64) * 32 + c8]);
        gload_lds16(&Bt[(size_t)(n0 + r0) * 256 + ks + c8],       &Bs[r0 * 32 + c8]);
        gload_lds16(&Bt[(size_t)(n0 + r0 + 64) * 256 + ks + c8],  &Bs[(r0 + 64) * 32 + c8]);
        __syncthreads();
        f16x8 af[4], bf[4];
#pragma unroll
        for (int a = 0; a < 4; a++) af[a] = *(const f16x8*)&As[(wm + a * 16 + c) * 32 + q * 8];
#pragma unroll
        for (int b = 0; b < 4; b++) bf[b] = *(const f16x8*)&Bs[(wn + b * 16 + c) * 32 + q * 8];
#pragma unroll
        for (int a = 0; a < 4; a++)
#pragma unroll
            for (int b = 0; b < 4; b++)
                acc[a][b] = __builtin_amdgcn_mfma_f32_16x16x32_f16(af[a], bf[b], acc[a][b], 0, 0, 0);
        __syncthreads();
    }
#pragma unroll
    for (int a = 0; a < 4; a++)
#pragma unroll
        for (int b = 0; b < 4; b++) {
            int row0 = m0 + wm + a * 16 + q * 4;
            int col = n0 + wn + b * 16 + c;
#pragma unroll
            for (int r = 0; r < 4; r++) {
                float v = acc[a][b][r];
                if (OUT_F32) ((float*)Cp)[(size_t)(row0 + r) * N + col] = v;
                else         ((f16*)Cp)[(size_t)(row0 + r) * N + col] = (f16)v;
            }
        }
}

// -------- fused attention: 1 block = (window, head), 4 waves share K/V LDS --------
// v9 (verified 57.3us): v5 structure + packed-f16 softmax (exp-domain bias).
template<bool HASB>
__device__ __forceinline__ void attn_tiles(
    const f16* __restrict__ qkv, const f16* __restrict__ ebH,
    f16* __restrict__ ctx, const f16* Ks, const f16* Vt,
    size_t base, int w, int h, int q, int c, int ta, int tb)
{
    const int iqa = ta * 16 + c;
    const int iqb = tb * 16 + c;
    const int iqac = iqa < NW ? iqa : NW - 1;
    const int iqbc = iqb < NW ? iqb : NW - 1;
    f16x8 qfa = *(const f16x8*)&qkv[base + (size_t)iqac * 768 + h * 32 + q * 8];
    f16x8 qfb{};
    if constexpr (HASB) qfb = *(const f16x8*)&qkv[base + (size_t)iqbc * 768 + h * 32 + q * 8];
    const f16* browA = ebH + (size_t)iqa * NWP;
    const f16* browB = ebH + (size_t)iqb * NWP;

    f32x4 o0a = {0.f,0.f,0.f,0.f}, o1a = {0.f,0.f,0.f,0.f};
    f32x4 o0b = {0.f,0.f,0.f,0.f}, o1b = {0.f,0.f,0.f,0.f};
    float lsa = 0.f, lsb = 0.f;
    const f32x4 z = {0.f, 0.f, 0.f, 0.f};
#pragma unroll
    for (int jt = 0; jt < NWP / 16; jt++) {
        const int jb = jt * 16;
        f16x8 kf = *(const f16x8*)&Ks[(jb + c) * 32 + q * 8];
        f16x4 v0 = *(const f16x4*)&Vt[c * VTP + jb + q * 4];
        f16x4 v1 = *(const f16x4*)&Vt[(16 + c) * VTP + jb + q * 4];

        f16x4 eba = *(const f16x4*)&browA[jb + q * 4];
        f32x4 sa = __builtin_amdgcn_mfma_f32_16x16x32_f16(kf, qfa, z, 0, 0, 0);
        f16x2 pla = pk_cvt(__builtin_amdgcn_exp2f(sa[0]), __builtin_amdgcn_exp2f(sa[1]));
        f16x2 pha = pk_cvt(__builtin_amdgcn_exp2f(sa[2]), __builtin_amdgcn_exp2f(sa[3]));
        f16x2 ela = { eba[0], eba[1] }, eha = { eba[2], eba[3] };
        pla *= ela; pha *= eha;                 // v_pk_mul_f16
        lsa = dot2acc(pla, lsa);
        lsa = dot2acc(pha, lsa);
        f16x4 pfa = { pla[0], pla[1], pha[0], pha[1] };
        o0a = __builtin_amdgcn_mfma_f32_16x16x16f16(v0, pfa, o0a, 0, 0, 0);
        o1a = __builtin_amdgcn_mfma_f32_16x16x16f16(v1, pfa, o1a, 0, 0, 0);

        if constexpr (HASB) {
            f16x4 ebb = *(const f16x4*)&browB[jb + q * 4];
            f32x4 sb = __builtin_amdgcn_mfma_f32_16x16x32_f16(kf, qfb, z, 0, 0, 0);
            f16x2 plb = pk_cvt(__builtin_amdgcn_exp2f(sb[0]), __builtin_amdgcn_exp2f(sb[1]));
            f16x2 phb = pk_cvt(__builtin_amdgcn_exp2f(sb[2]), __builtin_amdgcn_exp2f(sb[3]));
            f16x2 elb = { ebb[0], ebb[1] }, ehb = { ebb[2], ebb[3] };
            plb *= elb; phb *= ehb;
            lsb = dot2acc(plb, lsb);
            lsb = dot2acc(phb, lsb);
            f16x4 pfb = { plb[0], plb[1], phb[0], phb[1] };
            o0b = __builtin_amdgcn_mfma_f32_16x16x16f16(v0, pfb, o0b, 0, 0, 0);
            o1b = __builtin_amdgcn_mfma_f32_16x16x16f16(v1, pfb, o1b, 0, 0, 0);
        }
    }
    lsa += __shfl_xor(lsa, 16);
    lsa += __shfl_xor(lsa, 32);
    if (iqa < NW) {
        float inv = 1.f / lsa;
        size_t ob = (size_t)(w * NW + iqa) * 256 + h * 32;
        f16x4 s0 = { (f16)(o0a[0] * inv), (f16)(o0a[1] * inv),
                     (f16)(o0a[2] * inv), (f16)(o0a[3] * inv) };
        f16x4 s1 = { (f16)(o1a[0] * inv), (f16)(o1a[1] * inv),
                     (f16)(o1a[2] * inv), (f16)(o1a[3] * inv) };
        *(f16x4*)&ctx[ob + q * 4] = s0;
        *(f16x4*)&ctx[ob + 16 + q * 4] = s1;
    }
    if constexpr (HASB) {
        lsb += __shfl_xor(lsb, 16);
        lsb += __shfl_xor(lsb, 32);
        if (iqb < NW) {
            float inv = 1.f / lsb;
            size_t ob = (size_t)(w * NW + iqb) * 256 + h * 32;
            f16x4 s0 = { (f16)(o0b[0] * inv), (f16)(o0b[1] * inv),
                         (f16)(o0b[2] * inv), (f16)(o0b[3] * inv) };
            f16x4 s1 = { (f16)(o1b[0] * inv), (f16)(o1b[1] * inv),
                         (f16)(o1b[2] * inv), (f16)(o1b[3] * inv) };
            *(f16x4*)&ctx[ob + q * 4] = s0;
            *(f16x4*)&ctx[ob + 16 + q * 4] = s1;
        }
    }
}

__launch_bounds__(256, 3)
__global__ void attn_k(const f16* __restrict__ qkv, const f16* __restrict__ ebP,
                       f16* __restrict__ ctx) {
    const int w = blockIdx.x >> 3;
    const int h = blockIdx.x & 7;
    __shared__ f16 Ks[NWP * 32];       // [key][feat]
    __shared__ f16 Vt[32 * VTP];       // [dh][key] (transposed)
    const int t = threadIdx.x;
    const size_t base = (size_t)(w * NW) * 768;

    for (int u = t; u < NWP * 4; u += 256) {
        int row = u >> 2, un = u & 3;
        int rc = row < NW ? row : NW - 1;
        gload_lds16(&qkv[base + (size_t)rc * 768 + 256 + h * 32 + un * 8], &Ks[u * 8]);
    }
    for (int u = t; u < NWP * 4; u += 256) {
        int row = u >> 2, un = u & 3;
        if (row < NW) {
            uint4 val = *(const uint4*)&qkv[base + (size_t)row * 768 + 512 + h * 32 + un * 8];
            const f16* pv = (const f16*)&val;
#pragma unroll
            for (int e = 0; e < 8; e++) Vt[(un * 8 + e) * VTP + row] = pv[e];
        } else {
#pragma unroll
            for (int e = 0; e < 8; e++) Vt[(un * 8 + e) * VTP + row] = (f16)0.f;
        }
    }
    __syncthreads();

    const int wave = t >> 6, lane = t & 63;
    const int q = lane >> 4, c = lane & 15;
    const f16* ebH = ebP + (size_t)h * NWP * NWP;

#pragma unroll
    for (int pass = 0; pass < 3; pass++) {
        int p = wave + 4 * pass;
        if (p < 10)
            attn_tiles<true >(qkv, ebH, ctx, Ks, Vt, base, w, h, q, c, 2 * p, 2 * p + 1);
        else
            attn_tiles<false>(qkv, ebH, ctx, Ks, Vt, base, w, h, q, c, p + 10, p + 10);
    }
}

// ---------------- launch: 5 kernels ----------------
extern "C" void kernel_launch(void* const* d_in, const int* in_sizes, int n_in,
                              void* d_out, int out_size, void* d_ws, size_t ws_size,
                              hipStream_t stream) {
    const float* x    = (const float*)d_in[0];
    const float* wqkv = (const float*)d_in[1];
    const float* wout = (const float*)d_in[2];
    const float* tab  = (const float*)d_in[3];

    char* ws = (char*)d_ws;
    size_t off = 0;
    f16*   xb     = (f16*)(ws + off);   off += (size_t)MTOT * 256 * 2;
    f16*   wqkvT  = (f16*)(ws + off);   off += (size_t)768 * 256 * 2;
    f16*   woutT  = (f16*)(ws + off);   off += (size_t)256 * 256 * 2;
    f16*   ebP    = (f16*)(ws + off);   off += (size_t)8 * NWP * NWP * 2;
    f16*   qkvb   = (f16*)(ws + off);   off += (size_t)MTOT * 768 * 2;
    f16*   ctxb   = (f16*)(ws + off);   off += (size_t)MTOT * 256 * 2;
    if (ws_size < off) return;

    cvt_x <<<MTOT * 256 / 1024, 256, 0, stream>>>(x, xb);
    prep_k<<<1024 + 8 * NWP * NWP / 256, 256, 0, stream>>>(wqkv, wout, tab,
                                                           wqkvT, woutT, ebP);
    gemm_k<false><<<MTOT / 128 * 6, 256, 0, stream>>>(xb, wqkvT, qkvb, 768, 6);
    attn_k<<<128 * HEADS, 256, 0, stream>>>(qkvb, ebP, ctxb);
    gemm_k<true ><<<MTOT / 128 * 2, 256, 0, stream>>>(ctxb, woutT, d_out, 256, 2);
}